// Round 7
// baseline (1232.963 us; speedup 1.0000x reference)
//
#include <hip/hip_runtime.h>

// Compact Bilinear Pooling reformulated as per-batch Gram GEMM + count-sketch
// scatter:  y_b[d] = sum_{i,j} w1[i] w2[j] (X_b X_b^T)[i,j] [(h1[i]+h2[j])%D==d]
// Round 7: ABLATION ROUND. Five structural theories in, the ~400us invariant
// stands unexplained (MfmaUtil 9%, VALUBusy 7%, ~75% of cycles idle). Per the
// methodology: stop hypothesizing, ablate. Four template variants of the
// round-6 kernel run into a dummy buffer alongside the unchanged real kernel;
// the rocprof per-dispatch table gives each phase's marginal cost.
//   abl<3> = stage-DMA + vmcnt + barrier skeleton only
//   abl<1> = skeleton + ds_read + MFMA (results asm-sunk, no atomics)
//   abl<2> = skeleton + ds_add scatter (no reads/MFMA)
//   abl<4> = reads + MFMA + atomics, NO per-tile sync (buffers staged once)
//   cbp_gram6 = full (real output, within-probe baseline)

#define D_PROJ 16384
#define C_CH   2048
#define HW_N   196
#define NKS    7                 // k-steps of 32 (K padded 196 -> 224)
#define KPAD   (NKS * 32)
#define B_N    16
#define THREADS 512
#define NT     64                // j-tiles per block (1024 cols / 16)
#define BUFS   6
#define AHEAD  4
#define ROWSH  448               // shorts per row (hi 224 | lo 224, swizzled)

typedef short  short8 __attribute__((ext_vector_type(8)));
typedef float  f32x4  __attribute__((ext_vector_type(4)));

static __device__ inline unsigned short f2bf(float f) {
    union { float f; unsigned u; } a; a.f = f;
    unsigned u = a.u;
    return (unsigned short)((u + 0x7FFFu + ((u >> 16) & 1u)) >> 16);  // RNE
}
static __device__ inline float bf2f(unsigned short h) {
    union { unsigned u; float f; } a; a.u = ((unsigned)h) << 16;
    return a.f;
}
static __device__ inline f32x4 mfma16(short8 a, short8 b, f32x4 c) {
    return __builtin_amdgcn_mfma_f32_16x16x32_bf16(a, b, c, 0, 0, 0);
}

// native LDS fp32 atomic add (no return -> no CAS loop)
static __device__ inline void lds_fadd(float* p, float v) {
    unsigned off = (unsigned)(uintptr_t)p;
    asm volatile("ds_add_f32 %0, %1" :: "v"(off), "v"(v) : "memory");
}
// drain this wave's outstanding LDS ops (asm ds_add is invisible to compiler)
static __device__ inline void lds_drain() {
    asm volatile("s_waitcnt lgkmcnt(0)" ::: "memory");
    __builtin_amdgcn_sched_barrier(0);
}

// swizzled byte offset within a 896B row: block (ks,lo?,sub) XOR row-bits
static __device__ inline int swz_off(int ks, int lo64, int sub16, int row7) {
    return (((ks << 7) | lo64 | (sub16 << 4)) ^ (row7 << 4));
}

// ---- pre-convert: x (f32) -> split-bf16 hi/lo, swizzled rows of 896B ----
__global__ __launch_bounds__(256)
void cbp_convert(const float* __restrict__ x, unsigned short* __restrict__ ws) {
    const int id = blockIdx.x * 256 + threadIdx.x;
    const int total = B_N * C_CH * (KPAD / 8);
    if (id >= total) return;
    const int row = id / (KPAD / 8);
    const int sub = id - row * (KPAD / 8);   // 0..27
    const int k0  = sub * 8;
    const int ks  = k0 >> 5;
    const int s16 = (k0 >> 3) & 3;

    const float* xr = x + (size_t)row * HW_N;
    float v[8];
    if (k0 + 8 <= HW_N) {
        f32x4 p0 = *(const f32x4*)(xr + k0);
        f32x4 p1 = *(const f32x4*)(xr + k0 + 4);
#pragma unroll
        for (int e = 0; e < 4; ++e) { v[e] = p0[e]; v[4 + e] = p1[e]; }
    } else {
#pragma unroll
        for (int e = 0; e < 8; ++e) {
            const int k = k0 + e;
            v[e] = (k < HW_N) ? xr[k] : 0.0f;
        }
    }
    short8 hv, lv;
#pragma unroll
    for (int e = 0; e < 8; ++e) {
        unsigned short h = f2bf(v[e]);
        hv[e] = (short)h;
        lv[e] = (short)f2bf(v[e] - bf2f(h));
    }
    char* rowB = (char*)ws + (size_t)row * (ROWSH * 2);
    const int r7 = row & 7;
    *(short8*)(rowB + swz_off(ks, 0,  s16, r7)) = hv;
    *(short8*)(rowB + swz_off(ks, 64, s16, r7)) = lv;
}

// ---- stage one 16-row B tile into LDS via global_load_lds DMA ----
static __device__ inline void stage_issue(const unsigned short* __restrict__ src0,
                                          unsigned short* dst0, int wave, int lane) {
    if (lane < 56) {
#pragma unroll
        for (int hlf = 0; hlf < 2; ++hlf) {
            const int row = wave + hlf * 8;
            const unsigned short* s = src0 + (size_t)row * ROWSH + (size_t)lane * 8;
            unsigned short* d = dst0 + (size_t)row * ROWSH;
            __builtin_amdgcn_global_load_lds(
                (const __attribute__((address_space(1))) void*)s,
                (__attribute__((address_space(3))) void*)d, 16, 0, 0);
        }
    }
}

// ================= ABLATION VARIANTS (dummy output, DCE-guarded) =============
template<int V>
__global__ __launch_bounds__(THREADS, 2)
void cbp_abl(const unsigned short* __restrict__ ws,
             const float* __restrict__ w1f,
             const float* __restrict__ w2f,
             const int*   __restrict__ h1,
             const int*   __restrict__ h2,
             float*       __restrict__ dummy) {
    constexpr bool DO_READ = (V == 1 || V == 4);   // ds_read + MFMA
    constexpr bool DO_ATOM = (V == 2 || V == 4);   // ds_add scatter
    constexpr bool DO_PIPE = (V != 4);             // per-tile stage+vmcnt+barrier

    __shared__ __align__(16) float hist[D_PROJ];
    __shared__ __align__(16) unsigned short stage[BUFS][16 * ROWSH];
    __shared__ float w2sh[1024];
    __shared__ int   h2sh[1024];

    const int id   = blockIdx.x;
    const int b    = ((id & 7) << 1) | ((id >> 3) & 1);
    const int rest = id >> 4;
    const int j0   = (rest & 1) * 1024;
    const int i0   = (rest >> 1) * 256;

    const int tid  = threadIdx.x;
    const int wave = tid >> 6;
    const int lane = tid & 63;
    const int l15  = lane & 15;
    const int lgrp = lane >> 4;
    const int r7s  = (l15 & 7) << 4;

    for (int t = tid; t < D_PROJ / 4; t += THREADS)
        ((f32x4*)hist)[t] = f32x4{0.f, 0.f, 0.f, 0.f};
    for (int t = tid; t < 1024; t += THREADS) {
        w2sh[t] = w2f[j0 + t];
        h2sh[t] = h2[j0 + t];
    }

    short8 ah[2][NKS], al[2][NKS];
    int    binr[2][4];
    float  s1r[2][4];
#pragma unroll
    for (int s = 0; s < 2; ++s) {
        if constexpr (DO_READ) {
            const int irow = i0 + wave * 32 + s * 16 + l15;
            const char* rowA = (const char*)(ws + ((size_t)b * C_CH + irow) * ROWSH);
#pragma unroll
            for (int ks = 0; ks < NKS; ++ks) {
                ah[s][ks] = *(const short8*)(rowA + (((ks << 7) | (lgrp << 4)) ^ r7s));
                al[s][ks] = *(const short8*)(rowA + (((ks << 7) | 64 | (lgrp << 4)) ^ r7s));
            }
        }
#pragma unroll
        for (int r = 0; r < 4; ++r) {
            const int ir = i0 + wave * 32 + s * 16 + lgrp * 4 + r;
            binr[s][r] = h1[ir];
            s1r[s][r]  = w1f[ir];
        }
    }

    const unsigned short* jbase = ws + ((size_t)b * C_CH + j0) * ROWSH;
    if constexpr (DO_PIPE) {
#pragma unroll
        for (int p = 0; p < AHEAD; ++p)
            stage_issue(jbase + (size_t)p * 16 * ROWSH, stage[p], wave, lane);
        asm volatile("s_waitcnt lgkmcnt(0)\ns_barrier" ::: "memory");
    } else {
#pragma unroll
        for (int p = 0; p < BUFS; ++p)
            stage_issue(jbase + (size_t)p * 16 * ROWSH, stage[p], wave, lane);
        asm volatile("s_waitcnt vmcnt(0) lgkmcnt(0)\ns_barrier" ::: "memory");
    }

    for (int t = 0; t < NT; ++t) {
        if constexpr (DO_PIPE) {
            int tt = t + AHEAD; tt = (tt < NT) ? tt : (NT - 1);
            stage_issue(jbase + (size_t)tt * 16 * ROWSH, stage[(t + AHEAD) % BUFS], wave, lane);
            asm volatile("s_waitcnt vmcnt(8)" ::: "memory");
            __builtin_amdgcn_sched_barrier(0);
            asm volatile("s_barrier" ::: "memory");
            __builtin_amdgcn_sched_barrier(0);
        }

        f32x4 g0 = {0.f,0.f,0.f,0.f};
        f32x4 g1 = {0.f,0.f,0.f,0.f};
        if constexpr (DO_READ) {
            const char* srow = (const char*)&stage[t % BUFS][(size_t)l15 * ROWSH];
            f32x4 a0 = {0.f,0.f,0.f,0.f}, a1 = {0.f,0.f,0.f,0.f};
            f32x4 b0 = {0.f,0.f,0.f,0.f}, b1 = {0.f,0.f,0.f,0.f};
#pragma unroll
            for (int ks = 0; ks < NKS; ++ks) {
                const short8 bh = *(const short8*)(srow + (((ks << 7) | (lgrp << 4)) ^ r7s));
                const short8 bl = *(const short8*)(srow + (((ks << 7) | 64 | (lgrp << 4)) ^ r7s));
                if (ks & 1) {
                    a1 = mfma16(ah[0][ks], bh, a1);  b1 = mfma16(ah[1][ks], bh, b1);
                    a1 = mfma16(al[0][ks], bh, a1);  b1 = mfma16(al[1][ks], bh, b1);
                    a1 = mfma16(ah[0][ks], bl, a1);  b1 = mfma16(ah[1][ks], bl, b1);
                } else {
                    a0 = mfma16(ah[0][ks], bh, a0);  b0 = mfma16(ah[1][ks], bh, b0);
                    a0 = mfma16(al[0][ks], bh, a0);  b0 = mfma16(al[1][ks], bh, b0);
                    a0 = mfma16(ah[0][ks], bl, a0);  b0 = mfma16(ah[1][ks], bl, b0);
                }
            }
            g0 = a0 + a1;
            g1 = b0 + b1;
        }

        const float w2v = w2sh[t * 16 + l15];
        const int   h2v = h2sh[t * 16 + l15];
        if constexpr (DO_ATOM) {
#pragma unroll
            for (int r = 0; r < 4; ++r) {
                int bin = binr[0][r] + h2v;
                if (bin >= D_PROJ) bin -= D_PROJ;
                float v = DO_READ ? g0[r] * (s1r[0][r] * w2v) : s1r[0][r] * w2v;
                lds_fadd(&hist[bin], v);
            }
#pragma unroll
            for (int r = 0; r < 4; ++r) {
                int bin = binr[1][r] + h2v;
                if (bin >= D_PROJ) bin -= D_PROJ;
                float v = DO_READ ? g1[r] * (s1r[1][r] * w2v) : s1r[1][r] * w2v;
                lds_fadd(&hist[bin], v);
            }
        } else if constexpr (DO_READ) {
            // keep reads+MFMA live without atomics (rule #17)
            asm volatile("" :: "v"(g0[0]), "v"(g0[1]), "v"(g0[2]), "v"(g0[3]),
                              "v"(g1[0]), "v"(g1[1]), "v"(g1[2]), "v"(g1[3]));
        }
    }

    lds_drain();
    __syncthreads();
    // all ablation blocks store to the same dummy slot (benign races, never read)
    for (int t = tid; t < D_PROJ / 4; t += THREADS)
        ((f32x4*)dummy)[t] = ((const f32x4*)hist)[t];
}

// ================= FULL KERNEL (unchanged round-6, real output) ==============
__global__ __launch_bounds__(THREADS, 2)
void cbp_gram6(const unsigned short* __restrict__ ws,
               const float* __restrict__ w1f,
               const float* __restrict__ w2f,
               const int*   __restrict__ h1,
               const int*   __restrict__ h2,
               float*       __restrict__ part) {
    __shared__ __align__(16) float hist[D_PROJ];
    __shared__ __align__(16) unsigned short stage[BUFS][16 * ROWSH];
    __shared__ float w2sh[1024];
    __shared__ int   h2sh[1024];

    const int id   = blockIdx.x;
    const int b    = ((id & 7) << 1) | ((id >> 3) & 1);
    const int rest = id >> 4;
    const int j0   = (rest & 1) * 1024;
    const int i0   = (rest >> 1) * 256;

    const int tid  = threadIdx.x;
    const int wave = tid >> 6;
    const int lane = tid & 63;
    const int l15  = lane & 15;
    const int lgrp = lane >> 4;
    const int r7s  = (l15 & 7) << 4;

    for (int t = tid; t < D_PROJ / 4; t += THREADS)
        ((f32x4*)hist)[t] = f32x4{0.f, 0.f, 0.f, 0.f};
    for (int t = tid; t < 1024; t += THREADS) {
        w2sh[t] = w2f[j0 + t];
        h2sh[t] = h2[j0 + t];
    }

    short8 ah[2][NKS], al[2][NKS];
    int    binr[2][4];
    float  s1r[2][4];
#pragma unroll
    for (int s = 0; s < 2; ++s) {
        const int irow = i0 + wave * 32 + s * 16 + l15;
        const char* rowA = (const char*)(ws + ((size_t)b * C_CH + irow) * ROWSH);
#pragma unroll
        for (int ks = 0; ks < NKS; ++ks) {
            ah[s][ks] = *(const short8*)(rowA + (((ks << 7) | (lgrp << 4)) ^ r7s));
            al[s][ks] = *(const short8*)(rowA + (((ks << 7) | 64 | (lgrp << 4)) ^ r7s));
        }
#pragma unroll
        for (int r = 0; r < 4; ++r) {
            const int ir = i0 + wave * 32 + s * 16 + lgrp * 4 + r;
            binr[s][r] = h1[ir];
            s1r[s][r]  = w1f[ir];
        }
    }

    const unsigned short* jbase = ws + ((size_t)b * C_CH + j0) * ROWSH;
#pragma unroll
    for (int p = 0; p < AHEAD; ++p)
        stage_issue(jbase + (size_t)p * 16 * ROWSH, stage[p], wave, lane);

    asm volatile("s_waitcnt lgkmcnt(0)\ns_barrier" ::: "memory");

    for (int t = 0; t < NT; ++t) {
        int tt = t + AHEAD; tt = (tt < NT) ? tt : (NT - 1);
        stage_issue(jbase + (size_t)tt * 16 * ROWSH, stage[(t + AHEAD) % BUFS], wave, lane);
        asm volatile("s_waitcnt vmcnt(8)" ::: "memory");
        __builtin_amdgcn_sched_barrier(0);
        asm volatile("s_barrier" ::: "memory");
        __builtin_amdgcn_sched_barrier(0);

        const char* srow = (const char*)&stage[t % BUFS][(size_t)l15 * ROWSH];
        f32x4 a0 = {0.f,0.f,0.f,0.f}, a1 = {0.f,0.f,0.f,0.f};
        f32x4 b0 = {0.f,0.f,0.f,0.f}, b1 = {0.f,0.f,0.f,0.f};
#pragma unroll
        for (int ks = 0; ks < NKS; ++ks) {
            const short8 bh = *(const short8*)(srow + (((ks << 7) | (lgrp << 4)) ^ r7s));
            const short8 bl = *(const short8*)(srow + (((ks << 7) | 64 | (lgrp << 4)) ^ r7s));
            if (ks & 1) {
                a1 = mfma16(ah[0][ks], bh, a1);  b1 = mfma16(ah[1][ks], bh, b1);
                a1 = mfma16(al[0][ks], bh, a1);  b1 = mfma16(al[1][ks], bh, b1);
                a1 = mfma16(ah[0][ks], bl, a1);  b1 = mfma16(ah[1][ks], bl, b1);
            } else {
                a0 = mfma16(ah[0][ks], bh, a0);  b0 = mfma16(ah[1][ks], bh, b0);
                a0 = mfma16(al[0][ks], bh, a0);  b0 = mfma16(al[1][ks], bh, b0);
                a0 = mfma16(ah[0][ks], bl, a0);  b0 = mfma16(ah[1][ks], bl, b0);
            }
        }
        const float w2v = w2sh[t * 16 + l15];
        const int   h2v = h2sh[t * 16 + l15];
        const f32x4 g0 = a0 + a1;
        const f32x4 g1 = b0 + b1;
#pragma unroll
        for (int r = 0; r < 4; ++r) {
            int bin = binr[0][r] + h2v;
            if (bin >= D_PROJ) bin -= D_PROJ;
            lds_fadd(&hist[bin], g0[r] * (s1r[0][r] * w2v));
        }
#pragma unroll
        for (int r = 0; r < 4; ++r) {
            int bin = binr[1][r] + h2v;
            if (bin >= D_PROJ) bin -= D_PROJ;
            lds_fadd(&hist[bin], g1[r] * (s1r[1][r] * w2v));
        }
    }

    lds_drain();
    __syncthreads();
    float* pslot = part + ((size_t)(b * 16 + rest)) * D_PROJ;
    for (int t = tid; t < D_PROJ / 4; t += THREADS)
        ((f32x4*)pslot)[t] = ((const f32x4*)hist)[t];
}

// ---- reduce 16 partials per batch, signed-sqrt, L2 normalize ----
__global__ void cbp_finalize2(const float* __restrict__ part, float* __restrict__ y) {
    const int b   = blockIdx.x;
    const int tid = threadIdx.x;
    const float* pb = part + (size_t)b * 16 * D_PROJ;
    float* yb = y + (size_t)b * D_PROJ;
    __shared__ float partial[4];

    float ssum = 0.f;
    for (int t = tid; t < D_PROJ; t += 256) {
        float v = 0.f;
#pragma unroll
        for (int s = 0; s < 16; ++s) v += pb[(size_t)s * D_PROJ + t];
        float sg = copysignf(sqrtf(fabsf(v) + 1e-8f), v);
        yb[t] = sg;
        ssum += sg * sg;
    }
    const int lane = tid & 63, wv = tid >> 6;
#pragma unroll
    for (int off = 32; off > 0; off >>= 1) ssum += __shfl_down(ssum, off, 64);
    if (lane == 0) partial[wv] = ssum;
    __syncthreads();
    const float total = partial[0] + partial[1] + partial[2] + partial[3];
    const float inv = 1.0f / sqrtf(total + 1e-8f);
    for (int t = tid; t < D_PROJ; t += 256) yb[t] *= inv;
}

// ---------------- fallback (round-1 kernel, used if ws too small) --------------
static __device__ inline void cvt_split(const float (&v)[8], short8& hi, short8& lo) {
#pragma unroll
    for (int e = 0; e < 8; ++e) {
        unsigned short h = f2bf(v[e]);
        hi[e] = (short)h;
        lo[e] = (short)f2bf(v[e] - bf2f(h));
    }
}

__global__ __launch_bounds__(256, 2)
void cbp_gram_scatter(const float* __restrict__ x,
                      const float* __restrict__ w1f,
                      const float* __restrict__ w2f,
                      const int*   __restrict__ h1,
                      const int*   __restrict__ h2,
                      float*       __restrict__ y) {
    __shared__ float hist[D_PROJ];
    const int b    = blockIdx.y;
    const int i0   = blockIdx.x * 64;
    const int tid  = threadIdx.x;
    const int wave = tid >> 6;
    const int lane = tid & 63;
    const int l15  = lane & 15;
    const int lgrp = lane >> 4;

    for (int t = tid; t < D_PROJ; t += 256) hist[t] = 0.0f;
    const float* xb = x + (size_t)b * (C_CH * HW_N);

    const int    irow = i0 + wave * 16 + l15;
    const float* xa   = xb + (size_t)irow * HW_N;
    const float  w1s  = w1f[irow];
    short8 a_hi[NKS], a_lo[NKS];
#pragma unroll
    for (int ks = 0; ks < NKS; ++ks) {
        const int k0 = ks * 32 + lgrp * 8;
        float v[8];
#pragma unroll
        for (int e = 0; e < 8; ++e) {
            const int k = k0 + e;
            v[e] = (k < HW_N) ? xa[k] * w1s : 0.0f;
        }
        cvt_split(v, a_hi[ks], a_lo[ks]);
    }
    int bin1[4];
#pragma unroll
    for (int r = 0; r < 4; ++r) bin1[r] = h1[i0 + wave * 16 + lgrp * 4 + r];

    __syncthreads();

    for (int jt = 0; jt < C_CH / 16; ++jt) {
        const int    jrow = jt * 16 + l15;
        const float* xj   = xb + (size_t)jrow * HW_N;
        const float  w2s  = w2f[jrow];
        const int    h2j  = h2[jrow];
        f32x4 acc0 = {0.f, 0.f, 0.f, 0.f};
        f32x4 acc1 = {0.f, 0.f, 0.f, 0.f};
#pragma unroll
        for (int ks = 0; ks < NKS; ++ks) {
            const int k0 = ks * 32 + lgrp * 8;
            float v[8];
            if (ks < 6) {
                f32x4 p0 = *(const f32x4*)(xj + k0);
                f32x4 p1 = *(const f32x4*)(xj + k0 + 4);
#pragma unroll
                for (int e = 0; e < 4; ++e) { v[e] = p0[e]; v[4 + e] = p1[e]; }
            } else {
#pragma unroll
                for (int e = 0; e < 8; ++e) {
                    const int k = k0 + e;
                    v[e] = (k < HW_N) ? xj[k] : 0.0f;
                }
            }
#pragma unroll
            for (int e = 0; e < 8; ++e) v[e] *= w2s;
            short8 bhi, blo;
            cvt_split(v, bhi, blo);
            if (ks & 1) {
                acc1 = mfma16(a_hi[ks], bhi, acc1);
                acc1 = mfma16(a_hi[ks], blo, acc1);
                acc1 = mfma16(a_lo[ks], bhi, acc1);
            } else {
                acc0 = mfma16(a_hi[ks], bhi, acc0);
                acc0 = mfma16(a_hi[ks], blo, acc0);
                acc0 = mfma16(a_lo[ks], bhi, acc0);
            }
        }
        const f32x4 g = acc0 + acc1;
#pragma unroll
        for (int r = 0; r < 4; ++r) {
            int bin = bin1[r] + h2j;
            if (bin >= D_PROJ) bin -= D_PROJ;
            lds_fadd(&hist[bin], g[r]);
        }
    }

    lds_drain();
    __syncthreads();
    float* yb = y + (size_t)b * D_PROJ;
    for (int t = tid; t < D_PROJ; t += 256)
        atomicAdd(&yb[t], hist[t]);
}

__global__ void cbp_finalize(float* __restrict__ y) {
    const int b   = blockIdx.x;
    const int tid = threadIdx.x;
    float* yb = y + (size_t)b * D_PROJ;
    __shared__ float partial[4];

    float ssum = 0.f;
    for (int t = tid; t < D_PROJ; t += 256) {
        float v = yb[t];
        float s = copysignf(sqrtf(fabsf(v) + 1e-8f), v);
        yb[t] = s;
        ssum += s * s;
    }
    const int lane = tid & 63, wv = tid >> 6;
#pragma unroll
    for (int off = 32; off > 0; off >>= 1) ssum += __shfl_down(ssum, off, 64);
    if (lane == 0) partial[wv] = ssum;
    __syncthreads();
    const float total = partial[0] + partial[1] + partial[2] + partial[3];
    const float inv = 1.0f / sqrtf(total + 1e-8f);
    for (int t = tid; t < D_PROJ; t += 256) yb[t] *= inv;
}

extern "C" void kernel_launch(void* const* d_in, const int* in_sizes, int n_in,
                              void* d_out, int out_size, void* d_ws, size_t ws_size,
                              hipStream_t stream) {
    const float* x  = (const float*)d_in[0];
    const float* w1 = (const float*)d_in[1];
    const float* w2 = (const float*)d_in[2];
    const int*   h1 = (const int*)d_in[3];
    const int*   h2 = (const int*)d_in[4];
    float* y = (float*)d_out;

    const size_t need = (size_t)B_N * C_CH * ROWSH * 2 * sizeof(unsigned short);  // 58.72 MB
    const size_t planeBytes = (size_t)B_N * C_CH * ROWSH * sizeof(unsigned short);// 29.36 MB

    if (ws_size >= need) {
        unsigned short* wsp = (unsigned short*)d_ws;
        float* part  = (float*)((char*)d_ws + planeBytes);        // 256 slots, 16.78 MB
        float* dummy = part + (size_t)256 * D_PROJ;               // 64 KB shared dummy
        const int total = B_N * C_CH * (KPAD / 8);
        cbp_convert<<<(total + 255) / 256, 256, 0, stream>>>(x, wsp);
        // ---- ablation dispatches (dummy output; read durations from rocprof) ----
        cbp_abl<3><<<256, THREADS, 0, stream>>>(wsp, w1, w2, h1, h2, dummy);
        cbp_abl<1><<<256, THREADS, 0, stream>>>(wsp, w1, w2, h1, h2, dummy);
        cbp_abl<2><<<256, THREADS, 0, stream>>>(wsp, w1, w2, h1, h2, dummy);
        cbp_abl<4><<<256, THREADS, 0, stream>>>(wsp, w1, w2, h1, h2, dummy);
        // ---- real kernel (unchanged round-6) ----
        cbp_gram6<<<256, THREADS, 0, stream>>>(wsp, w1, w2, h1, h2, part);
        cbp_finalize2<<<B_N, 256, 0, stream>>>(part, y);
    } else {
        hipMemsetAsync(y, 0, (size_t)B_N * D_PROJ * sizeof(float), stream);
        dim3 grid(C_CH / 64, B_N);
        cbp_gram_scatter<<<grid, 256, 0, stream>>>(x, w1, w2, h1, h2, y);
        cbp_finalize<<<B_N, 256, 0, stream>>>(y);
    }
}

// Round 8
// 434.847 us; speedup vs baseline: 2.8354x; 2.8354x over previous
//
#include <hip/hip_runtime.h>

// Compact Bilinear Pooling reformulated as per-batch Gram GEMM + count-sketch
// scatter:  y_b[d] = sum_{i,j} w1[i] w2[j] (X_b X_b^T)[i,j] [(h1[i]+h2[j])%D==d]
// Round 8: the ablation showed the {ds_read,MFMA,ds_add} body IS the 395us
// (abl<4> no-pipeline == full). Mechanism: lgkmcnt is a per-wave FIFO; every
// compiler-emitted read-wait transitively retires the previous contended
// ds_add RMWs -> every tile serializes on atomic COMPLETION. Fix: fully
// hand-counted loop in inline asm -- reads for t+1 issued BEFORE adds of t,
// wait lgkmcnt(4) leaves the 4 newest adds in flight forever; vmcnt(6)
// counted staging; prologue fake-use fences so the compiler inserts no
// in-loop vmcnt/lgkmcnt of its own.

#define D_PROJ 16384
#define C_CH   2048
#define HW_N   196
#define NKS    7
#define KPAD   (NKS * 32)
#define B_N    16
#define THREADS 512
#define NT     128               // j-tiles per block (full 2048 cols)
#define BUFS   6
#define AHEAD  4
#define ROWSH  448               // shorts per row (hi 224 | lo 224, swizzled)
#define TILE_SH (16 * ROWSH)     // 7168 shorts per staged tile
#define TILE_B  (TILE_SH * 2)    // 14336 bytes

typedef short short8 __attribute__((ext_vector_type(8)));
typedef float f32x4  __attribute__((ext_vector_type(4)));
typedef int   iv4    __attribute__((ext_vector_type(4)));

static __device__ inline unsigned short f2bf(float f) {
    union { float f; unsigned u; } a; a.f = f;
    unsigned u = a.u;
    return (unsigned short)((u + 0x7FFFu + ((u >> 16) & 1u)) >> 16);  // RNE
}
static __device__ inline float bf2f(unsigned short h) {
    union { unsigned u; float f; } a; a.u = ((unsigned)h) << 16;
    return a.f;
}
static __device__ inline f32x4 mfma16(short8 a, short8 b, f32x4 c) {
    return __builtin_amdgcn_mfma_f32_16x16x32_bf16(a, b, c, 0, 0, 0);
}
static __device__ inline short8 as_s8(iv4 v) {
    union { iv4 i; short8 s; } u; u.i = v; return u.s;
}

#define RD128(dst, addr, OFF) \
    asm volatile("ds_read_b128 %0, %1 offset:" #OFF : "=v"(dst) : "v"(addr))
#define RD32(dst, addr) \
    asm volatile("ds_read_b32 %0, %1" : "=v"(dst) : "v"(addr))
#define DSADD(addr, val) \
    asm volatile("ds_add_f32 %0, %1" :: "v"(addr), "v"(val) : "memory")

// swizzled byte offset within a 896B row (convert-side)
static __device__ inline int swz_off(int ks, int lo64, int sub16, int row7) {
    return (((ks << 7) | lo64 | (sub16 << 4)) ^ (row7 << 4));
}

// ---- pre-convert: x (f32) -> split-bf16 hi/lo, swizzled rows of 896B ----
__global__ __launch_bounds__(256)
void cbp_convert(const float* __restrict__ x, unsigned short* __restrict__ ws) {
    const int id = blockIdx.x * 256 + threadIdx.x;
    const int total = B_N * C_CH * (KPAD / 8);
    if (id >= total) return;
    const int row = id / (KPAD / 8);
    const int sub = id - row * (KPAD / 8);
    const int k0  = sub * 8;
    const int ks  = k0 >> 5;
    const int s16 = (k0 >> 3) & 3;

    const float* xr = x + (size_t)row * HW_N;
    float v[8];
    if (k0 + 8 <= HW_N) {
        f32x4 p0 = *(const f32x4*)(xr + k0);
        f32x4 p1 = *(const f32x4*)(xr + k0 + 4);
#pragma unroll
        for (int e = 0; e < 4; ++e) { v[e] = p0[e]; v[4 + e] = p1[e]; }
    } else {
#pragma unroll
        for (int e = 0; e < 8; ++e) {
            const int k = k0 + e;
            v[e] = (k < HW_N) ? xr[k] : 0.0f;
        }
    }
    short8 hv, lv;
#pragma unroll
    for (int e = 0; e < 8; ++e) {
        unsigned short h = f2bf(v[e]);
        hv[e] = (short)h;
        lv[e] = (short)f2bf(v[e] - bf2f(h));
    }
    char* rowB = (char*)ws + (size_t)row * (ROWSH * 2);
    const int r7 = row & 7;
    *(short8*)(rowB + swz_off(ks, 0,  s16, r7)) = hv;
    *(short8*)(rowB + swz_off(ks, 64, s16, r7)) = lv;
}

// ---- stage one 16-row tile into LDS via global_load_lds DMA (2 vmcnt/wave) ----
static __device__ inline void stage_issue(const unsigned short* __restrict__ src0,
                                          unsigned short* dst0, int wave, int lane) {
    if (lane < 56) {
#pragma unroll
        for (int hlf = 0; hlf < 2; ++hlf) {
            const int row = wave + hlf * 8;
            const unsigned short* s = src0 + (size_t)row * ROWSH + (size_t)lane * 8;
            unsigned short* d = dst0 + (size_t)row * ROWSH;
            __builtin_amdgcn_global_load_lds(
                (const __attribute__((address_space(1))) void*)s,
                (__attribute__((address_space(3))) void*)d, 16, 0, 0);
        }
    }
}

// one pipeline iteration: consume regs C*, load next tile into L*
#define CBP_ITER(TT, CH, CL, CPK, LH, LL, LPK)  do {                           \
    int stg_t = (TT) + AHEAD; if (stg_t > NT - 1) stg_t = NT - 1;              \
    stage_issue(jbase + (size_t)stg_t * TILE_SH, stageMem + stg_woff, wave, lane); \
    stg_woff += TILE_SH; if (stg_woff == BUFS * TILE_SH) stg_woff = 0;         \
    asm volatile("s_waitcnt vmcnt(6)" ::: "memory");                           \
    asm volatile("s_barrier" ::: "memory");                                    \
    asm volatile("s_waitcnt lgkmcnt(4)" ::: "memory");                         \
    __builtin_amdgcn_sched_barrier(0);                                         \
    {                                                                          \
        unsigned rdA = rd_base_hi + rd_off;                                    \
        unsigned rdB = rd_base_lo + rd_off;                                    \
        rd_off += TILE_B; if (rd_off == BUFS * TILE_B) rd_off = 0;             \
        RD128(LH[0], rdA, 0);   RD128(LH[1], rdA, 128);                        \
        RD128(LH[2], rdA, 256); RD128(LH[3], rdA, 384);                        \
        RD128(LH[4], rdA, 512); RD128(LH[5], rdA, 640);                        \
        RD128(LH[6], rdA, 768);                                                \
        RD128(LL[0], rdB, 0);   RD128(LL[1], rdB, 128);                        \
        RD128(LL[2], rdB, 256); RD128(LL[3], rdB, 384);                        \
        RD128(LL[4], rdB, 512); RD128(LL[5], rdB, 640);                        \
        RD128(LL[6], rdB, 768);                                                \
        int tn = (TT) + 1; if (tn > NT - 1) tn = NT - 1;                       \
        unsigned pa = pair_lane + (unsigned)tn * 64u;                          \
        RD32(LPK, pa);                                                         \
    }                                                                          \
    f32x4 A0 = {0.f,0.f,0.f,0.f}, A1 = {0.f,0.f,0.f,0.f};                      \
    _Pragma("unroll")                                                          \
    for (int ks = 0; ks < NKS; ++ks) {                                         \
        short8 bh = as_s8(CH[ks]); short8 bl = as_s8(CL[ks]);                  \
        if (ks & 1) { A1 = mfma16(ah[ks], bh, A1); A1 = mfma16(al[ks], bh, A1);\
                      A1 = mfma16(ah[ks], bl, A1); }                           \
        else        { A0 = mfma16(ah[ks], bh, A0); A0 = mfma16(al[ks], bh, A0);\
                      A0 = mfma16(ah[ks], bl, A0); }                           \
    }                                                                          \
    const f32x4 g = A0 + A1;                                                   \
    const unsigned pk  = (unsigned)(CPK);                                      \
    const unsigned h2v = pk & 0x3FFFu;                                         \
    const unsigned sg2 = pk & 0x80000000u;                                     \
    _Pragma("unroll")                                                          \
    for (int r = 0; r < 4; ++r) {                                              \
        int bin = binr[r] + (int)h2v; if (bin >= D_PROJ) bin -= D_PROJ;        \
        unsigned vb = __float_as_uint(g[r]) ^ s1sg[r] ^ sg2;                   \
        DSADD(hist0 + (unsigned)bin * 4u, __uint_as_float(vb));                \
    }                                                                          \
} while (0)

// ---- main: hand-counted pipelined Gram MFMA + scatter ----
__global__ __launch_bounds__(THREADS, 2)
void cbp_gram8(const unsigned short* __restrict__ ws,
               const float* __restrict__ w1f,
               const float* __restrict__ w2f,
               const int*   __restrict__ h1,
               const int*   __restrict__ h2,
               float*       __restrict__ part) {
    __shared__ __align__(16) float hist[D_PROJ];                        // 64 KB
    __shared__ __align__(128) unsigned short stageMem[BUFS * TILE_SH];  // 84 KB
    __shared__ int pairsh[C_CH];                                        // 8 KB

    // XCD swizzle: id&7 -> XCD, batches {2x,2x+1} per XCD
    const int id   = blockIdx.x;                 // 0..255
    const int b    = ((id & 7) << 1) | ((id >> 3) & 1);
    const int rest = id >> 4;                    // 0..15 = i-chunk
    const int i0   = rest * 128;

    const int tid  = threadIdx.x;
    const int wave = tid >> 6;
    const int lane = tid & 63;
    const int l15  = lane & 15;
    const int lgrp = lane >> 4;
    const int r7s  = (l15 & 7) << 4;

    // hist zero + pack table (h2 | sign(w2)<<31)
    for (int t = tid; t < D_PROJ / 4; t += THREADS)
        ((f32x4*)hist)[t] = f32x4{0.f, 0.f, 0.f, 0.f};
    for (int j = tid; j < C_CH; j += THREADS)
        pairsh[j] = h2[j] | (w2f[j] < 0.f ? (int)0x80000000 : 0);

    // A fragments: 16 rows per wave, hi+lo (56 VGPR)
    short8 ah[NKS], al[NKS];
    {
        const int irow = i0 + wave * 16 + l15;
        const char* rowA = (const char*)(ws + ((size_t)(b * C_CH + irow)) * ROWSH);
#pragma unroll
        for (int ks = 0; ks < NKS; ++ks) {
            ah[ks] = *(const short8*)(rowA + (((ks << 7) | (lgrp << 4)) ^ r7s));
            al[ks] = *(const short8*)(rowA + (((ks << 7) | 64 | (lgrp << 4)) ^ r7s));
        }
    }
    int      binr[4];
    unsigned s1sg[4];
#pragma unroll
    for (int r = 0; r < 4; ++r) {
        const int ir = i0 + wave * 16 + lgrp * 4 + r;
        binr[r] = h1[ir];
        s1sg[r] = (w1f[ir] < 0.f) ? 0x80000000u : 0u;
    }

    // fake-use fences: force compiler vmcnt waits for all pre-loop loads HERE
#pragma unroll
    for (int ks = 0; ks < NKS; ++ks)
        asm volatile("" :: "v"(ah[ks]), "v"(al[ks]));
    asm volatile("" :: "v"(binr[0]), "v"(binr[1]), "v"(binr[2]), "v"(binr[3]));
    asm volatile("" :: "v"(s1sg[0]), "v"(s1sg[1]), "v"(s1sg[2]), "v"(s1sg[3]));
    asm volatile("s_waitcnt vmcnt(0)" ::: "memory");

    // lane-constant LDS byte addresses
    const unsigned XH = ((unsigned)(lgrp << 4)) ^ (unsigned)r7s;
    const unsigned stage0    = (unsigned)(uintptr_t)&stageMem[0];
    const unsigned rd_base_hi = stage0 + (unsigned)l15 * 896u + XH;
    const unsigned rd_base_lo = stage0 + (unsigned)l15 * 896u + (XH ^ 64u);
    const unsigned pair_lane  = (unsigned)(uintptr_t)&pairsh[0] + (unsigned)l15 * 4u;
    const unsigned hist0      = (unsigned)(uintptr_t)&hist[0];

    const unsigned short* jbase = ws + (size_t)b * C_CH * ROWSH;

    // prologue: stage tiles 0..3; tile0 landed; drain LDS writes; barrier
#pragma unroll
    for (int p = 0; p < AHEAD; ++p)
        stage_issue(jbase + (size_t)p * TILE_SH, stageMem + p * TILE_SH, wave, lane);
    asm volatile("s_waitcnt vmcnt(6)" ::: "memory");      // tile 0 (own 2 DMA) done
    asm volatile("s_waitcnt lgkmcnt(0)" ::: "memory");    // hist zero + pack stores
    asm volatile("s_barrier" ::: "memory");
    __builtin_amdgcn_sched_barrier(0);

    // reads(0) + 4 dummy adds (establish the "4 newest adds in flight" invariant)
    iv4 H0[NKS], L0[NKS], H1[NKS], L1[NKS];
    int PK0, PK1;
    {
        unsigned rdA = rd_base_hi, rdB = rd_base_lo;
        RD128(H0[0], rdA, 0);   RD128(H0[1], rdA, 128);
        RD128(H0[2], rdA, 256); RD128(H0[3], rdA, 384);
        RD128(H0[4], rdA, 512); RD128(H0[5], rdA, 640);
        RD128(H0[6], rdA, 768);
        RD128(L0[0], rdB, 0);   RD128(L0[1], rdB, 128);
        RD128(L0[2], rdB, 256); RD128(L0[3], rdB, 384);
        RD128(L0[4], rdB, 512); RD128(L0[5], rdB, 640);
        RD128(L0[6], rdB, 768);
        RD32(PK0, pair_lane);
        const float z = 0.0f;
        DSADD(hist0 + (unsigned)tid * 4u, z);
        DSADD(hist0 + (unsigned)tid * 4u, z);
        DSADD(hist0 + (unsigned)tid * 4u, z);
        DSADD(hist0 + (unsigned)tid * 4u, z);
    }

    int stg_woff = AHEAD * TILE_SH;   // next stage -> buf 4 (shorts)
    unsigned rd_off = TILE_B;         // next reads -> buf 1 (bytes)

    for (int t = 0; t < NT; t += 2) {
        CBP_ITER(t,     H0, L0, PK0, H1, L1, PK1);
        CBP_ITER(t + 1, H1, L1, PK1, H0, L0, PK0);
    }

    asm volatile("s_waitcnt lgkmcnt(0)" ::: "memory");    // commit all ds_adds
    __builtin_amdgcn_sched_barrier(0);
    asm volatile("s_barrier" ::: "memory");
    // plain vectorized store of this block's partial histogram
    float* pslot = part + ((size_t)(b * 16 + rest)) * D_PROJ;
    for (int t = tid; t < D_PROJ / 4; t += THREADS)
        ((f32x4*)pslot)[t] = ((const f32x4*)hist)[t];
}

// ---- reduce 16 partials per batch, signed-sqrt, L2 normalize ----
__global__ void cbp_finalize2(const float* __restrict__ part, float* __restrict__ y) {
    const int b   = blockIdx.x;
    const int tid = threadIdx.x;
    const float* pb = part + (size_t)b * 16 * D_PROJ;
    float* yb = y + (size_t)b * D_PROJ;
    __shared__ float partial[4];

    float ssum = 0.f;
    for (int t = tid; t < D_PROJ; t += 256) {
        float v = 0.f;
#pragma unroll
        for (int s = 0; s < 16; ++s) v += pb[(size_t)s * D_PROJ + t];
        float sg = copysignf(sqrtf(fabsf(v) + 1e-8f), v);
        yb[t] = sg;
        ssum += sg * sg;
    }
    const int lane = tid & 63, wv = tid >> 6;
#pragma unroll
    for (int off = 32; off > 0; off >>= 1) ssum += __shfl_down(ssum, off, 64);
    if (lane == 0) partial[wv] = ssum;
    __syncthreads();
    const float total = partial[0] + partial[1] + partial[2] + partial[3];
    const float inv = 1.0f / sqrtf(total + 1e-8f);
    for (int t = tid; t < D_PROJ; t += 256) yb[t] *= inv;
}

// ---------------- fallback (round-1 style, used if ws too small) --------------
static __device__ inline void cvt_split(const float (&v)[8], short8& hi, short8& lo) {
#pragma unroll
    for (int e = 0; e < 8; ++e) {
        unsigned short h = f2bf(v[e]);
        hi[e] = (short)h;
        lo[e] = (short)f2bf(v[e] - bf2f(h));
    }
}
static __device__ inline void lds_fadd(float* p, float v) {
    unsigned off = (unsigned)(uintptr_t)p;
    asm volatile("ds_add_f32 %0, %1" :: "v"(off), "v"(v) : "memory");
}

__global__ __launch_bounds__(256, 2)
void cbp_gram_scatter(const float* __restrict__ x,
                      const float* __restrict__ w1f,
                      const float* __restrict__ w2f,
                      const int*   __restrict__ h1,
                      const int*   __restrict__ h2,
                      float*       __restrict__ y) {
    __shared__ float hist[D_PROJ];
    const int b    = blockIdx.y;
    const int i0   = blockIdx.x * 64;
    const int tid  = threadIdx.x;
    const int wave = tid >> 6;
    const int lane = tid & 63;
    const int l15  = lane & 15;
    const int lgrp = lane >> 4;

    for (int t = tid; t < D_PROJ; t += 256) hist[t] = 0.0f;
    const float* xb = x + (size_t)b * (C_CH * HW_N);

    const int    irow = i0 + wave * 16 + l15;
    const float* xa   = xb + (size_t)irow * HW_N;
    const float  w1s  = w1f[irow];
    short8 a_hi[NKS], a_lo[NKS];
#pragma unroll
    for (int ks = 0; ks < NKS; ++ks) {
        const int k0 = ks * 32 + lgrp * 8;
        float v[8];
#pragma unroll
        for (int e = 0; e < 8; ++e) {
            const int k = k0 + e;
            v[e] = (k < HW_N) ? xa[k] * w1s : 0.0f;
        }
        cvt_split(v, a_hi[ks], a_lo[ks]);
    }
    int bin1[4];
#pragma unroll
    for (int r = 0; r < 4; ++r) bin1[r] = h1[i0 + wave * 16 + lgrp * 4 + r];

    __syncthreads();

    for (int jt = 0; jt < C_CH / 16; ++jt) {
        const int    jrow = jt * 16 + l15;
        const float* xj   = xb + (size_t)jrow * HW_N;
        const float  w2s  = w2f[jrow];
        const int    h2j  = h2[jrow];
        f32x4 acc0 = {0.f, 0.f, 0.f, 0.f};
        f32x4 acc1 = {0.f, 0.f, 0.f, 0.f};
#pragma unroll
        for (int ks = 0; ks < NKS; ++ks) {
            const int k0 = ks * 32 + lgrp * 8;
            float v[8];
            if (ks < 6) {
                f32x4 p0 = *(const f32x4*)(xj + k0);
                f32x4 p1 = *(const f32x4*)(xj + k0 + 4);
#pragma unroll
                for (int e = 0; e < 4; ++e) { v[e] = p0[e]; v[4 + e] = p1[e]; }
            } else {
#pragma unroll
                for (int e = 0; e < 8; ++e) {
                    const int k = k0 + e;
                    v[e] = (k < HW_N) ? xj[k] : 0.0f;
                }
            }
#pragma unroll
            for (int e = 0; e < 8; ++e) v[e] *= w2s;
            short8 bhi, blo;
            cvt_split(v, bhi, blo);
            if (ks & 1) {
                acc1 = mfma16(a_hi[ks], bhi, acc1);
                acc1 = mfma16(a_hi[ks], blo, acc1);
                acc1 = mfma16(a_lo[ks], bhi, acc1);
            } else {
                acc0 = mfma16(a_hi[ks], bhi, acc0);
                acc0 = mfma16(a_hi[ks], blo, acc0);
                acc0 = mfma16(a_lo[ks], bhi, acc0);
            }
        }
        const f32x4 g = acc0 + acc1;
#pragma unroll
        for (int r = 0; r < 4; ++r) {
            int bin = bin1[r] + h2j;
            if (bin >= D_PROJ) bin -= D_PROJ;
            lds_fadd(&hist[bin], g[r]);
        }
    }

    asm volatile("s_waitcnt lgkmcnt(0)" ::: "memory");
    __builtin_amdgcn_sched_barrier(0);
    __syncthreads();
    float* yb = y + (size_t)b * D_PROJ;
    for (int t = tid; t < D_PROJ; t += 256)
        atomicAdd(&yb[t], hist[t]);
}

__global__ void cbp_finalize(float* __restrict__ y) {
    const int b   = blockIdx.x;
    const int tid = threadIdx.x;
    float* yb = y + (size_t)b * D_PROJ;
    __shared__ float partial[4];

    float ssum = 0.f;
    for (int t = tid; t < D_PROJ; t += 256) {
        float v = yb[t];
        float s = copysignf(sqrtf(fabsf(v) + 1e-8f), v);
        yb[t] = s;
        ssum += s * s;
    }
    const int lane = tid & 63, wv = tid >> 6;
#pragma unroll
    for (int off = 32; off > 0; off >>= 1) ssum += __shfl_down(ssum, off, 64);
    if (lane == 0) partial[wv] = ssum;
    __syncthreads();
    const float total = partial[0] + partial[1] + partial[2] + partial[3];
    const float inv = 1.0f / sqrtf(total + 1e-8f);
    for (int t = tid; t < D_PROJ; t += 256) yb[t] *= inv;
}

extern "C" void kernel_launch(void* const* d_in, const int* in_sizes, int n_in,
                              void* d_out, int out_size, void* d_ws, size_t ws_size,
                              hipStream_t stream) {
    const float* x  = (const float*)d_in[0];
    const float* w1 = (const float*)d_in[1];
    const float* w2 = (const float*)d_in[2];
    const int*   h1 = (const int*)d_in[3];
    const int*   h2 = (const int*)d_in[4];
    float* y = (float*)d_out;

    const size_t need = (size_t)B_N * C_CH * ROWSH * 2 * sizeof(unsigned short);  // 58.72 MB (known-pass gate)
    const size_t planeBytes = (size_t)B_N * C_CH * ROWSH * sizeof(unsigned short);// 29.36 MB

    if (ws_size >= need) {
        unsigned short* wsp = (unsigned short*)d_ws;
        float* part = (float*)((char*)d_ws + planeBytes);   // 256 slots, 16.78 MB
        const int total = B_N * C_CH * (KPAD / 8);
        cbp_convert<<<(total + 255) / 256, 256, 0, stream>>>(x, wsp);
        cbp_gram8<<<256, THREADS, 0, stream>>>(wsp, w1, w2, h1, h2, part);
        cbp_finalize2<<<B_N, 256, 0, stream>>>(part, y);
    } else {
        hipMemsetAsync(y, 0, (size_t)B_N * D_PROJ * sizeof(float), stream);
        dim3 grid(C_CH / 64, B_N);
        cbp_gram_scatter<<<grid, 256, 0, stream>>>(x, w1, w2, h1, h2, y);
        cbp_finalize<<<B_N, 256, 0, stream>>>(y);
    }
}